// Round 13
// baseline (900.888 us; speedup 1.0000x reference)
//
#include <hip/hip_runtime.h>

// 3x3 stride-1 VALID conv, NCHW fp32 in/out, bf16 MFMA implicit GEMM.
// N=16, Cin=Cout=32, 512x512 -> 510x510.
// R13 = R12 (PT=256/RT=6, row-reuse, b128 LDS, store-bounce, 1 barrier/row)
// with ONE mechanism fix: __syncthreads() drains vmcnt(0) -- every prior
// "loads in flight across compute" claim was void (R9's 2-batch was null
// because the barrier drained BOTH batches). Replace with
//   s_waitcnt lgkmcnt(0) + raw s_barrier   (LDS publication only),
// and re-instate the two-batch pipeline: issue row ir+4 at iter ir, commit
// row ir+3 from the batch issued at iter ir-1. The compiler's per-register
// tracking then emits a COUNTED vmcnt (~9, never 0) at the commit, so ~17
// loads/thread stay in flight permanently (m201-verified toolchain
// behavior: raw s_barrier does NOT force vmcnt drain).
// Race audit (barrier placement identical to R12): stage-slot reads all
// retire before the barrier (MFMA consumes them in program order);
// commit-after-barrier writes slot ir%3, next read 2 barriers later;
// bounce writes pre-barrier, store-reads post-barrier, slot rewritten at
// ir+2 after another lgkm-barrier. Global loads are wave-private VGPRs.
// Registers: R12 ~117 + 9 (2nd batch) ~= 126 <= 128 cap. Tripwire:
// WRITE_SIZE inflation = scratch spill (R3/R10 lesson).

namespace {
constexpr int NI    = 16;
constexpr int C_IN  = 32;
constexpr int HI    = 512;
constexpr int WI    = 512;
constexpr int C_OUT = 32;
constexpr int HO    = 510;
constexpr int WO    = 510;

constexpr int RT    = 6;          // output rows per block (510/6 = 85 exact)
constexpr int PT    = 256;        // output x-pixels per block
constexpr int XCOLS = 264;        // staged px per row: 256 core + 8 halo
constexpr int PSTR  = 40;         // shorts per pixel (80B stride, 16B aligned)
constexpr int SLOTS = 3;          // staging row ring
constexpr int SLOTW = XCOLS * PSTR;       // 10560 shorts per stage slot
constexpr int OSTR  = 260;        // out-buffer px stride in f32 words (1040B)
constexpr int OSLOT = OSTR * 32;  // 8320 words per out slot
constexpr int LDS_BYTES = SLOTS * SLOTW * 2 + 2 * OSLOT * 4;  // 129920 B
constexpr int HIWI  = HI * WI;
constexpr int NT    = 1024;
}

typedef __attribute__((ext_vector_type(4))) float  floatx4;
typedef __attribute__((ext_vector_type(8))) __bf16 bf16x8;
typedef __attribute__((ext_vector_type(8))) unsigned short ushortx8;

// LDS-only barrier: publish ds_writes (lgkmcnt) WITHOUT draining global
// loads (vmcnt stays counted). "memory" clobber pins LDS ops on the
// correct side; sched_barrier stops the backend hoisting reads above.
__device__ __forceinline__ void bar_lds() {
  asm volatile("s_waitcnt lgkmcnt(0)" ::: "memory");
  __builtin_amdgcn_s_barrier();
  __builtin_amdgcn_sched_barrier(0);
}

// ---- weight prep: w [co][ci][3][3] f32 -> ws bf16 A-fragments [tap][h][lane][j]
// lane = quad*16 + l16; element j: co = h*16 + l16, ci = quad*8 + j.
__global__ void conv_wprep(const float* __restrict__ w, __bf16* __restrict__ ws) {
  const int t = threadIdx.x;
  for (int i = t; i < 9 * 2 * 64 * 8; i += 256) {
    const int j    = i & 7;
    const int lane = (i >> 3) & 63;
    const int h    = (i >> 9) & 1;
    const int tap  = i >> 10;
    const int co   = h * 16 + (lane & 15);
    const int ci   = (lane >> 4) * 8 + j;
    ws[i] = (__bf16)w[(co * C_IN + ci) * 9 + tap];
  }
}

__global__ __launch_bounds__(NT)
__attribute__((amdgpu_waves_per_eu(4, 4)))
void conv3x3_mfma(const float* __restrict__ x, const __bf16* __restrict__ ws,
                  const float* __restrict__ bias, float* __restrict__ out) {
  extern __shared__ __bf16 lds[];                       // stage ring
  float* outbuf = (float*)(lds + SLOTS * SLOTW);        // out ring

  const int t    = threadIdx.x;
  const int lane = t & 63;
  const int wv   = t >> 6;        // 0..15
  const int quad = lane >> 4;
  const int l16  = lane & 15;
  const int ch   = wv >> 3;       // co-half: channels [ch*16, ch*16+16)
  const int w8   = wv & 7;        // px window [w8*32, w8*32+32)

  const int x0 = blockIdx.x * PT;
  const int y0 = blockIdx.y * RT;
  const int n  = blockIdx.z;

  const float* xn = x + (size_t)n * C_IN * HIWI;

  // ---- staging geometry (R8): thread t covers core px = t&255, ci octet
  // cq = t>>8. Per (cq,k) instruction-group: 256 consecutive px = 1KB
  // contiguous per plane. Commit packs 8 bf16 -> one ds_write_b128.
  const int ps   = t & 255;
  const int cq   = t >> 8;                      // 0..3
  const int gofs = (cq * 8) * HIWI + x0 + ps;   // + k*HIWI + (y0+gr)*WI
  const int lofs = ps * PSTR + cq * 8;          // + slot*SLOTW

  // halo px 256..263 (x0=0: real; x0=256: clamped, feeds only invalid outputs)
  const bool hw  = (wv < 4);
  const int hci  = t >> 3;                      // 0..31 for t<256
  const int hpx  = 256 + (t & 7);
  int hgx = x0 + hpx; if (hgx > WI - 1) hgx = WI - 1;
  const int hgo  = hci * HIWI + hgx;
  const int hlo  = hpx * PSTR + hci;

  auto issue = [&](int gr, float (&b)[8], float& h) {   // 8(+1) loads, in flight
    const float* rb = xn + (size_t)(y0 + gr) * WI;
#pragma unroll
    for (int k = 0; k < 8; ++k) b[k] = rb[gofs + k * HIWI];
    if (hw) h = rb[hgo];
  };
  auto commit = [&](int slot, float (&b)[8], float h) { // cvt + one b128 write
    __bf16* s = lds + slot * SLOTW;
    union { __bf16 bb[8]; ushortx8 u; } pk;
#pragma unroll
    for (int k = 0; k < 8; ++k) pk.bb[k] = (__bf16)b[k];
    *reinterpret_cast<ushortx8*>(s + lofs) = pk.u;      // 16B aligned
    if (hw) s[hlo] = (__bf16)h;
  };

  // ---- prologue: rows 0..2 staged; then prime batch pipeline with row 3
  {
    float p0[8], p1[8], p2[8];
    float h0 = 0.f, h1 = 0.f, h2 = 0.f;
    issue(0, p0, h0); issue(1, p1, h1); issue(2, p2, h2);
    commit(0, p0, h0); commit(1, p1, h1); commit(2, p2, h2);
  }

  float fb[2][8];                 // two load batches in flight (parity ir&1)
  float fh[2] = {0.f, 0.f};
  issue(3, fb[1], fh[1]);         // row 3 -> committed at iter 0

  // ---- A fragments: 9 coalesced 16B loads from prepped ws (L2-resident).
  bf16x8 afrag[9];
#pragma unroll
  for (int tap = 0; tap < 9; ++tap)
    afrag[tap] = *reinterpret_cast<const bf16x8*>(ws + ((tap * 2 + ch) * 64 + lane) * 8);

  float bv[4];
#pragma unroll
  for (int r = 0; r < 4; ++r)
    bv[r] = bias[ch * 16 + quad * 4 + r];

  __syncthreads();                // one full barrier before the pipeline

  floatx4 acc[3][2];              // rotating: output row o lives in acc[o%3]

#pragma unroll
  for (int ir = 0; ir < RT + 2; ++ir) {           // input rows y0+0 .. y0+7
    // issue row ir+4 into this iteration's parity batch; the OTHER batch
    // (row ir+3, issued last iter) stays in flight until the counted-vmcnt
    // commit below. Raw barrier never drains vmcnt.
    if (ir + 4 <= RT + 1) issue(ir + 4, fb[ir & 1], fh[ir & 1]);

    if (ir < RT) {                                // output row ir starts here
#pragma unroll
      for (int f = 0; f < 2; ++f)
        acc[ir % 3][f] = floatx4{bv[0], bv[1], bv[2], bv[3]};
    }

    // read this input row's 6 B-fragments ONCE (single b128 each)
    bf16x8 bfr[2][3];
    const __bf16* sl = lds + (ir % SLOTS) * SLOTW + (w8 * 32 + l16) * PSTR + quad * 8;
#pragma unroll
    for (int f = 0; f < 2; ++f)
#pragma unroll
      for (int kx = 0; kx < 3; ++kx)
        bfr[f][kx] = *reinterpret_cast<const bf16x8*>(sl + (f * 16 + kx) * PSTR);

    // each fragment feeds up to 3 output rows (ky = ir - o)
#pragma unroll
    for (int ky = 0; ky < 3; ++ky) {
      const int o = ir - ky;
      if (o < 0 || o >= RT) continue;
#pragma unroll
      for (int kx = 0; kx < 3; ++kx)
#pragma unroll
        for (int f = 0; f < 2; ++f)
          acc[o % 3][f] = __builtin_amdgcn_mfma_f32_16x16x32_bf16(
              afrag[ky * 3 + kx], bfr[f][kx], acc[o % 3][f], 0, 0, 0);
    }

    const int o = ir - 2;              // output row completed this iter
    if (o >= 0) {
      // acc -> out-buffer [co][px] (scalar writes, 2-way banks = free class)
      float* ob = outbuf + (o & 1) * OSLOT;
#pragma unroll
      for (int f = 0; f < 2; ++f)
#pragma unroll
        for (int r = 0; r < 4; ++r)
          ob[(ch * 16 + quad * 4 + r) * OSTR + w8 * 32 + f * 16 + l16] = acc[o % 3][f][r];
    }

    bar_lds();                         // lgkm-only: global loads stay in flight

    // commit row ir+3 (batch from iter ir-1; compiler emits a COUNTED vmcnt
    // here -- newer batch + stores stay outstanding) into slot ir%3;
    // published by the barriers of iters ir+1/ir+2 before its read at ir+3.
    if (ir + 3 <= RT + 1) commit(ir % SLOTS, fb[(ir + 1) & 1], fh[(ir + 1) & 1]);

    if (o >= 0) {
      // coalesced store: wave wv stores plane p*16+wv, one dwordx4 instr
      // = 64 lanes x 16B = 1KB contiguous per plane per instruction.
      const float* ob = outbuf + (o & 1) * OSLOT;
#pragma unroll
      for (int p = 0; p < 2; ++p) {
        const int co = p * 16 + wv;
        const floatx4 v = *reinterpret_cast<const floatx4*>(ob + co * OSTR + 4 * lane);
        const int gx = x0 + 4 * lane;
        float* dst = out + ((size_t)(n * C_OUT + co) * HO + (y0 + o)) * WO + gx;
        if (gx + 3 < WO) {
          *reinterpret_cast<floatx4*>(dst) = v;
        } else {                       // only x0=256, lane 63: px 508..511 -> 2 valid
          if (gx < WO)     dst[0] = v.x;
          if (gx + 1 < WO) dst[1] = v.y;
          if (gx + 2 < WO) dst[2] = v.z;
        }
      }
    }
  }
}

extern "C" void kernel_launch(void* const* d_in, const int* in_sizes, int n_in,
                              void* d_out, int out_size, void* d_ws, size_t ws_size,
                              hipStream_t stream) {
  const float* x    = (const float*)d_in[0];
  const float* w    = (const float*)d_in[1];
  const float* bias = (const float*)d_in[2];
  float* out        = (float*)d_out;
  __bf16* ws        = (__bf16*)d_ws;          // needs 18432 B

  static bool lds_cfg = false;                // one-time, host-side, capture-safe
  if (!lds_cfg) {
    hipFuncSetAttribute((const void*)conv3x3_mfma,
                        hipFuncAttributeMaxDynamicSharedMemorySize, LDS_BYTES);
    lds_cfg = true;
  }

  conv_wprep<<<dim3(1), 256, 0, stream>>>(w, ws);

  dim3 grid(WI / PT, HO / RT, NI);  // 2 x 85 x 16 = 2720 blocks, 1024 threads
  conv3x3_mfma<<<grid, NT, LDS_BYTES, stream>>>(x, ws, bias, out);
}